// Round 5
// baseline (1703.836 us; speedup 1.0000x reference)
//
#include <hip/hip_runtime.h>
#include <hip/hip_bf16.h>
#include <stdint.h>

#define DM 4096
#define TWO_DM 8192
#define BATCH 8
#define SEQ 512
#define BS_ROWS (BATCH*SEQ)   /* 4096 */
#define LAMBDA_INIT 0.8f

typedef float f32x4 __attribute__((ext_vector_type(4)));
typedef __bf16 bf16x8 __attribute__((ext_vector_type(8)));

static __device__ __forceinline__ unsigned short f2bf(float f) {
  __hip_bfloat16 h = __float2bfloat16(f);
  return __builtin_bit_cast(unsigned short, h);
}

__global__ __launch_bounds__(256) void cast_f32_to_bf16(
    const float* __restrict__ in, unsigned short* __restrict__ out, int n4) {
  int stride = gridDim.x * 256;
  for (int i = blockIdx.x * 256 + threadIdx.x; i < n4; i += stride) {
    f32x4 v = reinterpret_cast<const f32x4*>(in)[i];
    ushort4 o;
    o.x = f2bf(v[0]); o.y = f2bf(v[1]); o.z = f2bf(v[2]); o.w = f2bf(v[3]);
    reinterpret_cast<ushort4*>(out)[i] = o;
  }
}

// C = A[M,K] * B[N,K]^T (bf16 in), optional bias[N] (f32) and scale.
// MODE 0: C f32 row-major [*, ldc];  MODE 1: C bf16 row-major [*, ldc];
// MODE 2: C bf16 "V-transposed":  C[((r>>9)*TWO_DM + c)*SEQ + (r&511)]  (ldc unused)
// Batched via blockIdx.z: zb=z&7, zh=z>>3; A += zb*aSB+zh*aSH; B += zb*bSB+zh*bSH; C += z*cSZ.
// Requires: M%128==0 (grid.y), N%128==0 (grid.x), K%32==0.
// m97 structure: 128x128 tile, 4 waves (2x2), BK=32, global_load_lds width 16.
template<int MODE, int HAS_BIAS>
__global__ __launch_bounds__(256) void gemm_bt(
    const unsigned short* __restrict__ A, const unsigned short* __restrict__ B,
    void* __restrict__ C, const float* __restrict__ bias,
    int K, int lda, int ldb, int ldc,
    long aSB, long aSH, long bSB, long bSH, long cSZ, float scale)
{
  __shared__ unsigned short lA[128 * 32];
  __shared__ unsigned short lB[128 * 32];

  const int tid  = threadIdx.x;
  const int lane = tid & 63;
  const int wave = tid >> 6;
  const int wr = wave >> 1, wc = wave & 1;      // 2x2 waves, each owns 64x64
  const int row0 = blockIdx.y * 128;
  const int col0 = blockIdx.x * 128;
  const int z  = blockIdx.z;
  const int zb = z & 7, zh = z >> 3;

  const unsigned short* Ap = A + (long)zb * aSB + (long)zh * aSH;
  const unsigned short* Bp = B + (long)zb * bSB + (long)zh * bSH;

  f32x4 acc[4][4] = {};

  // staging: 512 x 16B chunks cover one 128x32 bf16 tile; chunk f ->
  // row=f>>2, col8=(f&3)*8.  LDS dst is linear flat*16B (wave-uniform base
  // + lane*16 per global_load_lds semantics).
  const int f0 = tid,        r0 = f0 >> 2, c0 = (f0 & 3) * 8;
  const int f1 = tid + 256,  r1 = f1 >> 2, c1 = (f1 & 3) * 8;

  for (int k0 = 0; k0 < K; k0 += 32) {
    __builtin_amdgcn_global_load_lds(
        (const __attribute__((address_space(1))) void*)(Ap + (long)(row0 + r0) * lda + k0 + c0),
        (__attribute__((address_space(3))) void*)(lA + f0 * 8), 16, 0, 0);
    __builtin_amdgcn_global_load_lds(
        (const __attribute__((address_space(1))) void*)(Ap + (long)(row0 + r1) * lda + k0 + c1),
        (__attribute__((address_space(3))) void*)(lA + f1 * 8), 16, 0, 0);
    __builtin_amdgcn_global_load_lds(
        (const __attribute__((address_space(1))) void*)(Bp + (long)(col0 + r0) * ldb + k0 + c0),
        (__attribute__((address_space(3))) void*)(lB + f0 * 8), 16, 0, 0);
    __builtin_amdgcn_global_load_lds(
        (const __attribute__((address_space(1))) void*)(Bp + (long)(col0 + r1) * ldb + k0 + c1),
        (__attribute__((address_space(3))) void*)(lB + f1 * 8), 16, 0, 0);
    __syncthreads();

    bf16x8 af[4], bfr[4];
    #pragma unroll
    for (int m = 0; m < 4; ++m)
      af[m] = *reinterpret_cast<const bf16x8*>(
          &lA[(wr * 64 + m * 16 + (lane & 15)) * 32 + (lane >> 4) * 8]);
    #pragma unroll
    for (int n = 0; n < 4; ++n)
      bfr[n] = *reinterpret_cast<const bf16x8*>(
          &lB[(wc * 64 + n * 16 + (lane & 15)) * 32 + (lane >> 4) * 8]);
    #pragma unroll
    for (int m = 0; m < 4; ++m)
      #pragma unroll
      for (int n = 0; n < 4; ++n)
        acc[m][n] = __builtin_amdgcn_mfma_f32_16x16x32_bf16(af[m], bfr[n], acc[m][n], 0, 0, 0);
    __syncthreads();
  }

  // epilogue: C/D layout col=lane&15, row=(lane>>4)*4+reg (m89-verified)
  const long cOff = (long)z * cSZ;
  const int rbase = row0 + wr * 64;
  const int cbase = col0 + wc * 64;
  #pragma unroll
  for (int m = 0; m < 4; ++m) {
    #pragma unroll
    for (int n = 0; n < 4; ++n) {
      const int c = cbase + n * 16 + (lane & 15);
      const float bv = HAS_BIAS ? bias[c] : 0.0f;
      if (MODE == 2) {
        // V-transposed write: rows r..r+3 are contiguous in s -> one ushort4
        const int r  = rbase + m * 16 + (lane >> 4) * 4;   // within-batch rows
        const int b  = r >> 9, s0 = r & 511;               // tile never crosses batch
        ushort4 o;
        o.x = f2bf(acc[m][n][0] * scale + bv);
        o.y = f2bf(acc[m][n][1] * scale + bv);
        o.z = f2bf(acc[m][n][2] * scale + bv);
        o.w = f2bf(acc[m][n][3] * scale + bv);
        *reinterpret_cast<ushort4*>(
            (unsigned short*)C + ((long)b * TWO_DM + c) * SEQ + s0) = o;
      } else {
        #pragma unroll
        for (int j = 0; j < 4; ++j) {
          const int r = rbase + m * 16 + (lane >> 4) * 4 + j;
          const float v = acc[m][n][j] * scale + bv;
          if (MODE == 1) ((unsigned short*)C)[cOff + (long)r * ldc + c] = f2bf(v);
          else           ((float*)C)[cOff + (long)r * ldc + c] = v;
        }
      }
    }
  }
}

// S layout: [16][512][512] f32, z = half*8 + b.  One block per (b,q) row.
__global__ __launch_bounds__(512) void softmax_combine(
    const float* __restrict__ S,
    const float* __restrict__ lq1, const float* __restrict__ lk1,
    const float* __restrict__ lq2, const float* __restrict__ lk2,
    unsigned short* __restrict__ P)
{
  __shared__ float red[16];
  const int row = blockIdx.x;          // b*512 + q
  const int k = threadIdx.x;           // 0..511
  const int lane = k & 63, wid = k >> 6;
  const long off = (long)row * SEQ;
  float v1 = S[off + k];
  float v2 = S[(long)8 * SEQ * SEQ + off + k];
  float m1 = v1, m2 = v2;
  #pragma unroll
  for (int o = 32; o; o >>= 1) { m1 = fmaxf(m1, __shfl_xor(m1, o)); m2 = fmaxf(m2, __shfl_xor(m2, o)); }
  if (lane == 0) { red[wid] = m1; red[8 + wid] = m2; }
  __syncthreads();
  m1 = red[0]; m2 = red[8];
  #pragma unroll
  for (int i = 1; i < 8; ++i) { m1 = fmaxf(m1, red[i]); m2 = fmaxf(m2, red[8 + i]); }
  __syncthreads();
  const float e1 = __expf(v1 - m1), e2 = __expf(v2 - m2);
  float s1 = e1, s2 = e2;
  #pragma unroll
  for (int o = 32; o; o >>= 1) { s1 += __shfl_xor(s1, o); s2 += __shfl_xor(s2, o); }
  if (lane == 0) { red[wid] = s1; red[8 + wid] = s2; }
  __syncthreads();
  s1 = 0.f; s2 = 0.f;
  #pragma unroll
  for (int i = 0; i < 8; ++i) { s1 += red[i]; s2 += red[8 + i]; }
  const float lam = __expf(lq1[k] * lk1[k]) - __expf(lq2[k] * lk2[k]) + LAMBDA_INIT;
  P[off + k] = f2bf(e1 / s1 - lam * (e2 / s2));
}

extern "C" void kernel_launch(void* const* d_in, const int* in_sizes, int n_in,
                              void* d_out, int out_size, void* d_ws, size_t ws_size,
                              hipStream_t stream) {
  const float* x    = (const float*)d_in[0];
  const float* wq_w = (const float*)d_in[1];
  const float* wq_b = (const float*)d_in[2];
  const float* wk_w = (const float*)d_in[3];
  const float* wk_b = (const float*)d_in[4];
  const float* wv_w = (const float*)d_in[5];
  const float* wv_b = (const float*)d_in[6];
  const float* lq1  = (const float*)d_in[7];
  const float* lk1  = (const float*)d_in[8];
  const float* lq2  = (const float*)d_in[9];
  const float* lk2  = (const float*)d_in[10];

  const size_t MB = 1024ull * 1024;

  // GUARD: the only way this kernel can kill a container is OOB writes when
  // ws_size < what the layout below assumes. If undersized, emit zeros:
  // clean absmax-8.125 failure = diagnostic signature, no crash.
  if (ws_size < 160 * MB) {
    hipMemsetAsync(d_out, 0, (size_t)out_size * sizeof(float), stream);
    return;
  }

  // ws layout (peak 160 MB):
  //   [0,32)    xb bf16 [4096][4096]      (dead after K proj)
  //               -> then sbuf f32 [16][512][512] at [0,16), pb bf16 at [16,20)
  //   [32,96)   vtb bf16 [8][8192][512]   (persists to PV)
  //   [96,160)  wb  bf16 [8192][4096]     (weight staging, reused x3)
  // d_out (128 MB f32) doubles as scratch: qb bf16 at +0, kb bf16 at +64MB;
  // both dead before the final PV write to d_out.
  char* ws = (char*)d_ws;
  unsigned short* xb   = (unsigned short*)(ws);
  float*          sbuf = (float*)(ws);
  unsigned short* pb   = (unsigned short*)(ws + 16 * MB);
  unsigned short* vtb  = (unsigned short*)(ws + 32 * MB);
  unsigned short* wb   = (unsigned short*)(ws + 96 * MB);
  unsigned short* qb   = (unsigned short*)(d_out);
  unsigned short* kb   = (unsigned short*)((char*)d_out + 64 * MB);

  const float scaleQK = 0.04419417382415922f;   // 1/sqrt(512)

  cast_f32_to_bf16<<<2048, 256, 0, stream>>>(x, xb, (BS_ROWS * DM) / 4);

  // V projection first, writing V^T directly (vtb[b][d][s])
  cast_f32_to_bf16<<<2048, 256, 0, stream>>>(wv_w, wb, (TWO_DM * DM) / 4);
  gemm_bt<2, 1><<<dim3(TWO_DM / 128, BS_ROWS / 128, 1), 256, 0, stream>>>(
      xb, wb, vtb, wv_b, DM, DM, DM, 0, 0, 0, 0, 0, 0, 1.0f);
  // Q projection -> qb (in d_out)
  cast_f32_to_bf16<<<2048, 256, 0, stream>>>(wq_w, wb, (TWO_DM * DM) / 4);
  gemm_bt<1, 1><<<dim3(TWO_DM / 128, BS_ROWS / 128, 1), 256, 0, stream>>>(
      xb, wb, qb, wq_b, DM, DM, DM, TWO_DM, 0, 0, 0, 0, 0, 1.0f);
  // K projection -> kb (in d_out)
  cast_f32_to_bf16<<<2048, 256, 0, stream>>>(wk_w, wb, (TWO_DM * DM) / 4);
  gemm_bt<1, 1><<<dim3(TWO_DM / 128, BS_ROWS / 128, 1), 256, 0, stream>>>(
      xb, wb, kb, wk_b, DM, DM, DM, TWO_DM, 0, 0, 0, 0, 0, 1.0f);

  // QK^T per (b, half): z = half*8 + b; sbuf overlays dead xb
  gemm_bt<0, 0><<<dim3(SEQ / 128, SEQ / 128, 16), 256, 0, stream>>>(
      qb, kb, sbuf, nullptr, DM, TWO_DM, TWO_DM, SEQ,
      (long)SEQ * TWO_DM, DM, (long)SEQ * TWO_DM, DM, (long)SEQ * SEQ, scaleQK);

  softmax_combine<<<BS_ROWS, 512, 0, stream>>>(sbuf, lq1, lk1, lq2, lk2, pb);

  // PV: out[b] = P[b] @ V[b]  (vtb is B^T layout); overwrites qb/kb (dead)
  gemm_bt<0, 0><<<dim3(TWO_DM / 128, SEQ / 128, 8), 256, 0, stream>>>(
      pb, vtb, (float*)d_out, nullptr, SEQ, SEQ, SEQ, TWO_DM,
      (long)SEQ * SEQ, 0, (long)TWO_DM * SEQ, 0, (long)SEQ * TWO_DM, 1.0f);
}

// Round 6
// 1416.733 us; speedup vs baseline: 1.2027x; 1.2027x over previous
//
#include <hip/hip_runtime.h>
#include <hip/hip_bf16.h>
#include <stdint.h>

#define DM 4096
#define TWO_DM 8192
#define BATCH 8
#define SEQ 512
#define BS_ROWS (BATCH*SEQ)   /* 4096 */
#define LAMBDA_INIT 0.8f

typedef float f32x4 __attribute__((ext_vector_type(4)));
typedef __bf16 bf16x8 __attribute__((ext_vector_type(8)));

static __device__ __forceinline__ unsigned short f2bf(float f) {
  __hip_bfloat16 h = __float2bfloat16(f);
  return __builtin_bit_cast(unsigned short, h);
}

__global__ __launch_bounds__(256) void cast_f32_to_bf16(
    const float* __restrict__ in, unsigned short* __restrict__ out, int n4) {
  int stride = gridDim.x * 256;
  for (int i = blockIdx.x * 256 + threadIdx.x; i < n4; i += stride) {
    f32x4 v = reinterpret_cast<const f32x4*>(in)[i];
    ushort4 o;
    o.x = f2bf(v[0]); o.y = f2bf(v[1]); o.z = f2bf(v[2]); o.w = f2bf(v[3]);
    reinterpret_cast<ushort4*>(out)[i] = o;
  }
}

// ---------------------------------------------------------------------------
// 256x256 8-phase GEMM (projections): C = A[M,K] * B[N,K]^T + bias, bf16 in.
// MODE 1: C bf16 row-major [*, TWO_DM];  MODE 2: C bf16 V-transposed
//   C[((r>>9)*TWO_DM + c)*SEQ + (r&511)].
// 8 waves (2Mx4N), BK=64, LDS 128KB = {A,B} x [2 buf][2 ksub] x 256x32 bf16.
// T2 chunk-XOR swizzle (read + pre-swizzled global source), T3/T4 counted
// vmcnt(6) at phases 4/8, T5 setprio, T1 XCD swizzle.
// Race-freedom: phase p reads quarter (ksub=p>>1 within its K-tile); each
// stage targets the region whose last read completed at the previous phase's
// ending barrier; vmcnt(6) at ph4/ph8 guarantees landing 3+ stages back.
// ---------------------------------------------------------------------------
#define STG(SMAT, SBUF, SKS, SKT)                                              \
  {                                                                            \
    const unsigned short* _s0 = ((SMAT) ? b_src0 : a_src0) + (SKT)*64 + (SKS)*32; \
    const unsigned short* _s1 = ((SMAT) ? b_src1 : a_src1) + (SKT)*64 + (SKS)*32; \
    unsigned short* _d = lds + ((SMAT)?32768:0) + ((SBUF)*2+(SKS))*8192 + tid*8;  \
    __builtin_amdgcn_global_load_lds((const __attribute__((address_space(1))) void*)_s0, \
        (__attribute__((address_space(3))) void*)_d, 16, 0, 0);                \
    __builtin_amdgcn_global_load_lds((const __attribute__((address_space(1))) void*)_s1, \
        (__attribute__((address_space(3))) void*)(_d + 4096), 16, 0, 0);       \
  }

#define PHASE(BUF, KS, MO, RB, DOSTG, SMAT, SBUF, SKS, SKT, DOVM)              \
  {                                                                            \
    _Pragma("unroll") for (int m = 0; m < 4; ++m) {                            \
      const int row = wm*128 + ((MO)+m)*16 + fr;                               \
      const int gp = g ^ (row & 3) ^ ((row >> 2) & 3);                         \
      af[m] = *reinterpret_cast<const bf16x8*>(                                \
          lds + ((BUF)*2+(KS))*8192 + row*32 + gp*8);                          \
    }                                                                          \
    if (RB) {                                                                  \
      _Pragma("unroll") for (int n = 0; n < 4; ++n) {                          \
        const int row = wn*64 + n*16 + fr;                                     \
        const int gp = g ^ (row & 3) ^ ((row >> 2) & 3);                       \
        bfr[n] = *reinterpret_cast<const bf16x8*>(                             \
            lds + 32768 + ((BUF)*2+(KS))*8192 + row*32 + gp*8);                \
      }                                                                        \
    }                                                                          \
    if (DOSTG) STG(SMAT, SBUF, SKS, SKT);                                      \
    __builtin_amdgcn_sched_barrier(0);                                         \
    __builtin_amdgcn_s_barrier();                                              \
    __builtin_amdgcn_s_setprio(1);                                             \
    _Pragma("unroll") for (int m = 0; m < 4; ++m)                              \
      _Pragma("unroll") for (int n = 0; n < 4; ++n)                            \
        acc[(MO)+m][n] = __builtin_amdgcn_mfma_f32_16x16x32_bf16(              \
            af[m], bfr[n], acc[(MO)+m][n], 0, 0, 0);                           \
    __builtin_amdgcn_s_setprio(0);                                             \
    __builtin_amdgcn_sched_barrier(0);                                         \
    if (DOVM) { asm volatile("s_waitcnt vmcnt(6)" ::: "memory"); }             \
    __builtin_amdgcn_s_barrier();                                              \
  }

template<int MODE>
__global__ __launch_bounds__(512, 2) void gemm256_proj(
    const unsigned short* __restrict__ A, const unsigned short* __restrict__ B,
    void* __restrict__ C, const float* __restrict__ bias,
    int K, int lda, int ldb, int ldc)
{
  __shared__ unsigned short lds[65536];   // 128 KiB

  const int tid  = threadIdx.x;
  const int lane = tid & 63;
  const int wid  = tid >> 6;
  const int wm = wid >> 2;                // 0..1
  const int wn = wid & 3;                 // 0..3
  const int fr = lane & 15;
  const int g  = lane >> 4;               // 16B chunk selector

  // T1: bijective XCD swizzle (nwg = gridDim.x*gridDim.y, multiple of 8)
  const int nwg  = gridDim.x * gridDim.y;
  const int flat = blockIdx.y * gridDim.x + blockIdx.x;
  const int swz  = (flat & 7) * (nwg >> 3) + (flat >> 3);
  const int bx = swz % gridDim.x;
  const int by = swz / gridDim.x;
  const int row0 = by * 256;
  const int col0 = bx * 256;

  // per-thread staging sources: slot s = tid (+512); row = s>>2,
  // source chunk = (s&3) ^ ((s>>2)&3) ^ ((s>>4)&3)  (inverse of read swizzle)
  const int srow = tid >> 2;
  const int gq   = (tid & 3) ^ ((tid >> 2) & 3) ^ ((tid >> 4) & 3);
  const unsigned short* a_src0 = A + (long)(row0 + srow) * lda + gq * 8;
  const unsigned short* a_src1 = A + (long)(row0 + 128 + srow) * lda + gq * 8;
  const unsigned short* b_src0 = B + (long)(col0 + srow) * ldb + gq * 8;
  const unsigned short* b_src1 = B + (long)(col0 + 128 + srow) * ldb + gq * 8;

  f32x4 acc[8][4] = {};
  bf16x8 af[4], bfr[4];

  // prologue: tile0 fully, tile1 minus A1
  STG(1,0,0, 0); STG(0,0,0, 0); STG(1,0,1, 0); STG(0,0,1, 0);
  asm volatile("s_waitcnt vmcnt(4)" ::: "memory");
  STG(1,1,0, 1); STG(0,1,0, 1); STG(1,1,1, 1);
  asm volatile("s_waitcnt vmcnt(6)" ::: "memory");
  __builtin_amdgcn_s_barrier();

  const int nt = K >> 6;                  // K-tiles (even, >=4)
  for (int i = 0; i <= nt/2 - 2; ++i) {
    const int t = 2 * i;
    PHASE(0,0,0, 1, 1, 0,1,1, t+1, 0)    // stage A1(t+1) -> A[1][k1]
    PHASE(0,0,4, 0, 1, 1,0,0, t+2, 0)    // stage B0(t+2) -> B[0][k0]
    PHASE(0,1,0, 1, 1, 0,0,0, t+2, 0)    // stage A0(t+2) -> A[0][k0]
    PHASE(0,1,4, 0, 1, 1,0,1, t+2, 1)    // stage B1(t+2) -> B[0][k1]; vmcnt(6)
    PHASE(1,0,0, 1, 1, 0,0,1, t+2, 0)    // stage A1(t+2) -> A[0][k1]
    PHASE(1,0,4, 0, 1, 1,1,0, t+3, 0)    // stage B0(t+3) -> B[1][k0]
    PHASE(1,1,0, 1, 1, 0,1,0, t+3, 0)    // stage A0(t+3) -> A[1][k0]
    PHASE(1,1,4, 0, 1, 1,1,1, t+3, 1)    // stage B1(t+3) -> B[1][k1]; vmcnt(6)
  }
  // epilogue: last missing stage, drain, compute tiles nt-2 (buf0), nt-1 (buf1)
  STG(0,1,1, nt-1);
  asm volatile("s_waitcnt vmcnt(0)" ::: "memory");
  __builtin_amdgcn_s_barrier();
  PHASE(0,0,0, 1, 0, 0,0,0,0, 0)
  PHASE(0,0,4, 0, 0, 0,0,0,0, 0)
  PHASE(0,1,0, 1, 0, 0,0,0,0, 0)
  PHASE(0,1,4, 0, 0, 0,0,0,0, 0)
  PHASE(1,0,0, 1, 0, 0,0,0,0, 0)
  PHASE(1,0,4, 0, 0, 0,0,0,0, 0)
  PHASE(1,1,0, 1, 0, 0,0,0,0, 0)
  PHASE(1,1,4, 0, 0, 0,0,0,0, 0)

  // C-write: C/D layout col=lane&15, row=(lane>>4)*4+reg (m89-verified)
  const int rb0 = row0 + wm * 128;
  const int cb0 = col0 + wn * 64;
  #pragma unroll
  for (int m = 0; m < 8; ++m) {
    #pragma unroll
    for (int n = 0; n < 4; ++n) {
      const int c = cb0 + n * 16 + fr;
      const float bv = bias[c];
      if (MODE == 2) {
        const int r  = rb0 + m * 16 + g * 4;
        const int b  = r >> 9, s0 = r & 511;     // 256-tile never crosses batch
        ushort4 o;
        o.x = f2bf(acc[m][n][0] + bv);
        o.y = f2bf(acc[m][n][1] + bv);
        o.z = f2bf(acc[m][n][2] + bv);
        o.w = f2bf(acc[m][n][3] + bv);
        *reinterpret_cast<ushort4*>(
            (unsigned short*)C + ((long)b * TWO_DM + c) * SEQ + s0) = o;
      } else {
        #pragma unroll
        for (int j = 0; j < 4; ++j) {
          const int r = rb0 + m * 16 + g * 4 + j;
          ((unsigned short*)C)[(long)r * ldc + c] = f2bf(acc[m][n][j] + bv);
        }
      }
    }
  }
}

// ---------------------------------------------------------------------------
// m97-structure 128x128 GEMM (QK^T and PV), unchanged from round 5.
// ---------------------------------------------------------------------------
template<int MODE, int HAS_BIAS>
__global__ __launch_bounds__(256) void gemm_bt(
    const unsigned short* __restrict__ A, const unsigned short* __restrict__ B,
    void* __restrict__ C, const float* __restrict__ bias,
    int K, int lda, int ldb, int ldc,
    long aSB, long aSH, long bSB, long bSH, long cSZ, float scale)
{
  __shared__ unsigned short lA[128 * 32];
  __shared__ unsigned short lB[128 * 32];

  const int tid  = threadIdx.x;
  const int lane = tid & 63;
  const int wave = tid >> 6;
  const int wr = wave >> 1, wc = wave & 1;
  const int row0 = blockIdx.y * 128;
  const int col0 = blockIdx.x * 128;
  const int z  = blockIdx.z;
  const int zb = z & 7, zh = z >> 3;

  const unsigned short* Ap = A + (long)zb * aSB + (long)zh * aSH;
  const unsigned short* Bp = B + (long)zb * bSB + (long)zh * bSH;

  f32x4 acc[4][4] = {};

  const int f0 = tid,        r0 = f0 >> 2, c0 = (f0 & 3) * 8;
  const int f1 = tid + 256,  r1 = f1 >> 2, c1 = (f1 & 3) * 8;

  for (int k0 = 0; k0 < K; k0 += 32) {
    __builtin_amdgcn_global_load_lds(
        (const __attribute__((address_space(1))) void*)(Ap + (long)(row0 + r0) * lda + k0 + c0),
        (__attribute__((address_space(3))) void*)(lA + f0 * 8), 16, 0, 0);
    __builtin_amdgcn_global_load_lds(
        (const __attribute__((address_space(1))) void*)(Ap + (long)(row0 + r1) * lda + k0 + c1),
        (__attribute__((address_space(3))) void*)(lA + f1 * 8), 16, 0, 0);
    __builtin_amdgcn_global_load_lds(
        (const __attribute__((address_space(1))) void*)(Bp + (long)(col0 + r0) * ldb + k0 + c0),
        (__attribute__((address_space(3))) void*)(lB + f0 * 8), 16, 0, 0);
    __builtin_amdgcn_global_load_lds(
        (const __attribute__((address_space(1))) void*)(Bp + (long)(col0 + r1) * ldb + k0 + c1),
        (__attribute__((address_space(3))) void*)(lB + f1 * 8), 16, 0, 0);
    __syncthreads();

    bf16x8 af[4], bfr[4];
    #pragma unroll
    for (int m = 0; m < 4; ++m)
      af[m] = *reinterpret_cast<const bf16x8*>(
          &lA[(wr * 64 + m * 16 + (lane & 15)) * 32 + (lane >> 4) * 8]);
    #pragma unroll
    for (int n = 0; n < 4; ++n)
      bfr[n] = *reinterpret_cast<const bf16x8*>(
          &lB[(wc * 64 + n * 16 + (lane & 15)) * 32 + (lane >> 4) * 8]);
    #pragma unroll
    for (int m = 0; m < 4; ++m)
      #pragma unroll
      for (int n = 0; n < 4; ++n)
        acc[m][n] = __builtin_amdgcn_mfma_f32_16x16x32_bf16(af[m], bfr[n], acc[m][n], 0, 0, 0);
    __syncthreads();
  }

  const long cOff = (long)z * cSZ;
  const int rbase = row0 + wr * 64;
  const int cbase = col0 + wc * 64;
  #pragma unroll
  for (int m = 0; m < 4; ++m) {
    #pragma unroll
    for (int n = 0; n < 4; ++n) {
      const int c = cbase + n * 16 + (lane & 15);
      const float bv = HAS_BIAS ? bias[c] : 0.0f;
      #pragma unroll
      for (int j = 0; j < 4; ++j) {
        const int r = rbase + m * 16 + (lane >> 4) * 4 + j;
        const float v = acc[m][n][j] * scale + bv;
        if (MODE == 1) ((unsigned short*)C)[cOff + (long)r * ldc + c] = f2bf(v);
        else           ((float*)C)[cOff + (long)r * ldc + c] = v;
      }
    }
  }
}

// S layout: [16][512][512] f32, z = half*8 + b.  One block per (b,q) row.
__global__ __launch_bounds__(512) void softmax_combine(
    const float* __restrict__ S,
    const float* __restrict__ lq1, const float* __restrict__ lk1,
    const float* __restrict__ lq2, const float* __restrict__ lk2,
    unsigned short* __restrict__ P)
{
  __shared__ float red[16];
  const int row = blockIdx.x;
  const int k = threadIdx.x;
  const int lane = k & 63, wid = k >> 6;
  const long off = (long)row * SEQ;
  float v1 = S[off + k];
  float v2 = S[(long)8 * SEQ * SEQ + off + k];
  float m1 = v1, m2 = v2;
  #pragma unroll
  for (int o = 32; o; o >>= 1) { m1 = fmaxf(m1, __shfl_xor(m1, o)); m2 = fmaxf(m2, __shfl_xor(m2, o)); }
  if (lane == 0) { red[wid] = m1; red[8 + wid] = m2; }
  __syncthreads();
  m1 = red[0]; m2 = red[8];
  #pragma unroll
  for (int i = 1; i < 8; ++i) { m1 = fmaxf(m1, red[i]); m2 = fmaxf(m2, red[8 + i]); }
  __syncthreads();
  const float e1 = __expf(v1 - m1), e2 = __expf(v2 - m2);
  float s1 = e1, s2 = e2;
  #pragma unroll
  for (int o = 32; o; o >>= 1) { s1 += __shfl_xor(s1, o); s2 += __shfl_xor(s2, o); }
  if (lane == 0) { red[wid] = s1; red[8 + wid] = s2; }
  __syncthreads();
  s1 = 0.f; s2 = 0.f;
  #pragma unroll
  for (int i = 0; i < 8; ++i) { s1 += red[i]; s2 += red[8 + i]; }
  const float lam = __expf(lq1[k] * lk1[k]) - __expf(lq2[k] * lk2[k]) + LAMBDA_INIT;
  P[off + k] = f2bf(e1 / s1 - lam * (e2 / s2));
}

extern "C" void kernel_launch(void* const* d_in, const int* in_sizes, int n_in,
                              void* d_out, int out_size, void* d_ws, size_t ws_size,
                              hipStream_t stream) {
  const float* x    = (const float*)d_in[0];
  const float* wq_w = (const float*)d_in[1];
  const float* wq_b = (const float*)d_in[2];
  const float* wk_w = (const float*)d_in[3];
  const float* wk_b = (const float*)d_in[4];
  const float* wv_w = (const float*)d_in[5];
  const float* wv_b = (const float*)d_in[6];
  const float* lq1  = (const float*)d_in[7];
  const float* lk1  = (const float*)d_in[8];
  const float* lq2  = (const float*)d_in[9];
  const float* lk2  = (const float*)d_in[10];

  const size_t MB = 1024ull * 1024;
  if (ws_size < 160 * MB) {   // diagnostic guard: zeros instead of OOB writes
    hipMemsetAsync(d_out, 0, (size_t)out_size * sizeof(float), stream);
    return;
  }

  // ws layout (peak 160 MB):
  //   [0,32)   xb bf16 [4096][4096] -> later sbuf f32 [16][512][512] + pb
  //   [32,96)  vtb bf16 [8][8192][512]
  //   [96,160) wb  bf16 [8192][4096]
  // d_out doubles as scratch: qb at +0, kb at +64MB (dead before PV write).
  char* ws = (char*)d_ws;
  unsigned short* xb   = (unsigned short*)(ws);
  float*          sbuf = (float*)(ws);
  unsigned short* pb   = (unsigned short*)(ws + 16 * MB);
  unsigned short* vtb  = (unsigned short*)(ws + 32 * MB);
  unsigned short* wb   = (unsigned short*)(ws + 96 * MB);
  unsigned short* qb   = (unsigned short*)(d_out);
  unsigned short* kb   = (unsigned short*)((char*)d_out + 64 * MB);

  const float scaleQK = 0.04419417382415922f;   // 1/sqrt(512)
  const dim3 pgrid(TWO_DM / 256, BS_ROWS / 256, 1);   // 32 x 16 = 512 WGs

  cast_f32_to_bf16<<<2048, 256, 0, stream>>>(x, xb, (BS_ROWS * DM) / 4);

  // V projection (writes V^T directly)
  cast_f32_to_bf16<<<2048, 256, 0, stream>>>(wv_w, wb, (TWO_DM * DM) / 4);
  gemm256_proj<2><<<pgrid, 512, 0, stream>>>(xb, wb, vtb, wv_b, DM, DM, DM, 0);
  // Q projection -> qb (in d_out)
  cast_f32_to_bf16<<<2048, 256, 0, stream>>>(wq_w, wb, (TWO_DM * DM) / 4);
  gemm256_proj<1><<<pgrid, 512, 0, stream>>>(xb, wb, qb, wq_b, DM, DM, DM, TWO_DM);
  // K projection -> kb (in d_out)
  cast_f32_to_bf16<<<2048, 256, 0, stream>>>(wk_w, wb, (TWO_DM * DM) / 4);
  gemm256_proj<1><<<pgrid, 512, 0, stream>>>(xb, wb, kb, wk_b, DM, DM, DM, TWO_DM);

  // QK^T per (b, half): z = half*8 + b; sbuf overlays dead xb
  gemm_bt<0, 0><<<dim3(SEQ / 128, SEQ / 128, 16), 256, 0, stream>>>(
      qb, kb, sbuf, nullptr, DM, TWO_DM, TWO_DM, SEQ,
      (long)SEQ * TWO_DM, DM, (long)SEQ * TWO_DM, DM, (long)SEQ * SEQ, scaleQK);

  softmax_combine<<<BS_ROWS, 512, 0, stream>>>(sbuf, lq1, lk1, lq2, lk2, pb);

  // PV: out[b] = P[b] @ V[b] (vtb is B^T layout); overwrites qb/kb (dead)
  gemm_bt<0, 0><<<dim3(TWO_DM / 128, SEQ / 128, 8), 256, 0, stream>>>(
      pb, vtb, (float*)d_out, nullptr, SEQ, SEQ, SEQ, TWO_DM,
      (long)SEQ * SEQ, 0, (long)TWO_DM * SEQ, 0, (long)SEQ * TWO_DM, 1.0f);
}